// Round 11
// baseline (863.270 us; speedup 1.0000x reference)
//
#include <hip/hip_runtime.h>

#define ND 100000
#define DD 128
#define HH 256
#define EE 640000
#define LL 5

typedef __attribute__((ext_vector_type(8))) short short8;
typedef __attribute__((ext_vector_type(4))) short short4v;
typedef __attribute__((ext_vector_type(4))) float f32x4;
typedef __attribute__((ext_vector_type(4))) unsigned u32x4;
typedef __attribute__((ext_vector_type(8))) _Float16 half8;
typedef __attribute__((ext_vector_type(4))) _Float16 half4;
typedef __attribute__((ext_vector_type(2))) _Float16 half2v;

static __device__ __forceinline__ short f2h(float f) {
    return __builtin_bit_cast(short, (_Float16)f);
}

// pack two fp32 -> packed fp16 pair (v_cvt_pkrtz_f16_f32, 1 instr)
static __device__ __forceinline__ half2v pk2(float a, float b) {
    return __builtin_bit_cast(half2v, __builtin_amdgcn_cvt_pkrtz(a, b));
}

static __device__ __forceinline__ half8 ld8(const short* p) {
    return __builtin_bit_cast(half8, *reinterpret_cast<const short8*>(p));
}

// ---------------------------------------------------------------------------
// setup: blocks [0,640) fold BN into weights (fp16 [n][k] pack);
//        blocks [640,13140) convert x fp32 -> fp16 into hbufA;
//        blocks [13140,15640) histogram dst degrees (cnt pre-zeroed).
// ---------------------------------------------------------------------------
__global__ __launch_bounds__(256) void setup(
    const float* __restrict__ W1, const float* __restrict__ b1,
    const float* __restrict__ g1, const float* __restrict__ bb1,
    const float* __restrict__ m1, const float* __restrict__ v1,
    const float* __restrict__ W2, const float* __restrict__ b2,
    const float* __restrict__ g2, const float* __restrict__ bb2,
    const float* __restrict__ m2, const float* __restrict__ v2,
    const float* __restrict__ x, const int* __restrict__ dst,
    short* __restrict__ W1p, float* __restrict__ b1e,
    short* __restrict__ W2p, float* __restrict__ b2e,
    short* __restrict__ hb, int* __restrict__ cnt)
{
    int bx = blockIdx.x;
    int tid = threadIdx.x;
    if (bx < 640) {
        int id = bx * 256 + tid;
        if (id < LL * HH * DD) {
            int l = id >> 15;
            int rem = id & 32767;
            {
                int n = rem >> 7, k = rem & 127;
                float s = g1[l * HH + n] * rsqrtf(v1[l * HH + n] + 1e-5f);
                W1p[id] = f2h(W1[l * 32768 + k * HH + n] * s);
            }
            {
                int n2 = rem >> 8, k2 = rem & 255;
                float s = g2[l * DD + n2] * rsqrtf(v2[l * DD + n2] + 1e-5f);
                W2p[id] = f2h(W2[l * 32768 + k2 * DD + n2] * s);
            }
        }
        if (id < LL * HH) {
            float s = g1[id] * rsqrtf(v1[id] + 1e-5f);
            b1e[id] = (b1[id] - m1[id]) * s + bb1[id];
        }
        if (id < LL * DD) {
            float s = g2[id] * rsqrtf(v2[id] + 1e-5f);
            b2e[id] = (b2[id] - m2[id]) * s + bb2[id];
        }
    } else if (bx < 13140) {
        int i = (bx - 640) * 256 + tid;          // ND*DD/4 = 3,200,000 float4s
        float4 v = reinterpret_cast<const float4*>(x)[i];
        half2v p0 = pk2(v.x, v.y);
        half2v p1 = pk2(v.z, v.w);
        half4 hv = __builtin_shufflevector(p0, p1, 0, 1, 2, 3);
        reinterpret_cast<short4v*>(hb)[i] = __builtin_bit_cast(short4v, hv);
    } else {
        int e = (bx - 13140) * 256 + tid;
        if (e < EE) atomicAdd(&cnt[dst[e]], 1);
    }
}

// per-block inclusive scan of cnt (in place) + block totals
__global__ __launch_bounds__(256) void scan_block(int* __restrict__ cnt, int* __restrict__ bsum)
{
    __shared__ int buf[256];
    int tid = threadIdx.x;
    int idx = blockIdx.x * 256 + tid;
    int v = (idx < ND) ? cnt[idx] : 0;
    buf[tid] = v;
    __syncthreads();
    int sum = v;
    for (int off = 1; off < 256; off <<= 1) {
        int t = (tid >= off) ? buf[tid - off] : 0;
        __syncthreads();
        sum += t;
        buf[tid] = sum;
        __syncthreads();
    }
    if (idx < ND) cnt[idx] = sum;
    if (tid == 255) bsum[blockIdx.x] = sum;
}

// merged: each block computes its exclusive prefix over bsum, then rowst
__global__ __launch_bounds__(256) void apply_offs2(const int* __restrict__ cnt,
                                                   const int* __restrict__ bsum,
                                                   int* __restrict__ rowst)
{
    __shared__ int sred[256];
    int tid = threadIdx.x;
    int partial = 0;
    for (int i = tid; i < blockIdx.x; i += 256) partial += bsum[i];
    sred[tid] = partial;
    __syncthreads();
    for (int off = 128; off > 0; off >>= 1) {
        if (tid < off) sred[tid] += sred[tid + off];
        __syncthreads();
    }
    int boff = sred[0];
    int idx = blockIdx.x * 256 + tid;
    if (idx < ND) rowst[idx + 1] = cnt[idx] + boff;
    if (idx == 0) rowst[0] = 0;
}

__global__ __launch_bounds__(256) void fill_csr(const int* __restrict__ src,
                                                const int* __restrict__ dst,
                                                const int* __restrict__ rowstart,
                                                int* __restrict__ cursor,
                                                int* __restrict__ csr)
{
    int e = blockIdx.x * 256 + threadIdx.x;
    if (e < EE) {
        int d = dst[e];
        int p = atomicAdd(&cursor[d], 1);
        csr[rowstart[d] + p] = src[e];
    }
}

// ---------------------------------------------------------------------------
// Fused GIN layer — WAVE-AUTONOMOUS: each wave computes the full layer for
// its own 16 nodes. Zero barriers, zero LDS, no inter-wave coupling.
//   Lane (quad, l16) owns node l16 of the wave's group, channels
//   [32k + quad*8, +8) for k=0..3 — so gathered agg IS the GEMM1 B-fragment
//   (B[k][n]: col=lane&15, k=quad*8+j per 32-slice). GEMM1 C-layout
//   (row=zcol=quad*4+reg, col=node=l16) is redistributed to GEMM2 B-fragments
//   by 64 in-wave __shfl ops confined to the 4 quads of the same node column.
//   Weights stream from L2 (128 KB/wave, L2-resident).
// hb_in != hb_out (cross-block WAR hazard).
// ---------------------------------------------------------------------------
__global__ __launch_bounds__(256, 4) void layer_fused(
    const short* __restrict__ hb_in,
    const int* __restrict__ rowst,
    const int* __restrict__ csr,
    const short* __restrict__ W1l,    // [256 zcols][128 k] fp16
    const float* __restrict__ b1l,    // [256]
    const short* __restrict__ W2l,    // [128 outcols][256 k] fp16
    const float* __restrict__ b2l,    // [128]
    short* __restrict__ hb_out, float* __restrict__ f_out, int last)
{
    const int tid = threadIdx.x;
    const int wv = blockIdx.x * 4 + (tid >> 6);     // global wave id
    const int lane = tid & 63;
    const int quad = lane >> 4;
    const int l16 = lane & 15;
    const int node = wv * 16 + l16;
    const bool valid = (node < ND);
    const int nc = valid ? node : 0;

    // ---- gather: ag[k] = channels [32k + quad*8, +8) of agg(node) ----
    half8 ag[4];
    {
        const short* rp = hb_in + (size_t)nc * DD + quad * 8;
        #pragma unroll
        for (int k = 0; k < 4; ++k) ag[k] = ld8(rp + k * 32);

        int i = 0, e = 0;
        if (valid) { i = rowst[node]; e = rowst[node + 1]; }
        for (; i + 1 < e; i += 2) {
            int n0 = csr[i], n1 = csr[i + 1];
            const short* p0 = hb_in + (size_t)n0 * DD + quad * 8;
            const short* p1 = hb_in + (size_t)n1 * DD + quad * 8;
            half8 a[4], b[4];
            #pragma unroll
            for (int k = 0; k < 4; ++k) a[k] = ld8(p0 + k * 32);
            #pragma unroll
            for (int k = 0; k < 4; ++k) b[k] = ld8(p1 + k * 32);
            #pragma unroll
            for (int k = 0; k < 4; ++k) ag[k] = ag[k] + (a[k] + b[k]);
        }
        if (i < e) {
            const short* p0 = hb_in + (size_t)csr[i] * DD + quad * 8;
            half8 a[4];
            #pragma unroll
            for (int k = 0; k < 4; ++k) a[k] = ld8(p0 + k * 32);
            #pragma unroll
            for (int k = 0; k < 4; ++k) ag[k] = ag[k] + a[k];
        }
    }

    // ---- GEMM1: 16 zcol-tiles x K=128; bias+ReLU+pack per tile ----
    const f32x4 zero4 = {0.f, 0.f, 0.f, 0.f};
    unsigned pkz[16][2];   // packed z: pkz[T][p] = zcols (16T+quad*4+2p, +1) of node l16
    #pragma unroll
    for (int T = 0; T < 16; ++T) {
        f32x4 acc = zero4;
        #pragma unroll
        for (int ks = 0; ks < 4; ++ks) {
            half8 aw = ld8(&W1l[(T * 16 + l16) * DD + ks * 32 + quad * 8]);
            acc = __builtin_amdgcn_mfma_f32_16x16x32_f16(aw, ag[ks], acc, 0, 0, 0);
        }
        float4 bi = *reinterpret_cast<const float4*>(&b1l[T * 16 + quad * 4]);
        pkz[T][0] = __builtin_bit_cast(unsigned,
            pk2(fmaxf(acc[0] + bi.x, 0.f), fmaxf(acc[1] + bi.y, 0.f)));
        pkz[T][1] = __builtin_bit_cast(unsigned,
            pk2(fmaxf(acc[2] + bi.z, 0.f), fmaxf(acc[3] + bi.w, 0.f)));
    }

    // ---- in-wave z redistribution: build GEMM2 B-fragments bf[ks] ----
    // dest lane (quad,l16) pair m needs zcols (32ks + quad*8 + 2m, +1) of node
    // l16, held by lane (srcq = (quad&1)*2 + (m>>1))*16 + l16, tile
    // 2ks + (quad>>1), packed reg m&1. Exchange never leaves the node column.
    u32x4 bf[8];
    #pragma unroll
    for (int ks = 0; ks < 8; ++ks) {
        #pragma unroll
        for (int m = 0; m < 4; ++m) {
            int sl = ((quad & 1) * 2 + (m >> 1)) * 16 + l16;
            unsigned lo = (unsigned)__shfl((int)pkz[2 * ks][m & 1], sl, 64);
            unsigned hi = (unsigned)__shfl((int)pkz[2 * ks + 1][m & 1], sl, 64);
            bf[ks][m] = (quad < 2) ? lo : hi;
        }
    }

    // ---- GEMM2: 8 outcol-tiles x K=256; bias (+ReLU) + store per tile ----
    #pragma unroll
    for (int O = 0; O < 8; ++O) {
        f32x4 acc = zero4;
        #pragma unroll
        for (int ks = 0; ks < 8; ++ks) {
            half8 aw = ld8(&W2l[(O * 16 + l16) * HH + ks * 32 + quad * 8]);
            acc = __builtin_amdgcn_mfma_f32_16x16x32_f16(
                aw, __builtin_bit_cast(half8, bf[ks]), acc, 0, 0, 0);
        }
        float4 bi = *reinterpret_cast<const float4*>(&b2l[O * 16 + quad * 4]);
        if (valid) {
            int oc = O * 16 + quad * 4;
            float v0 = acc[0] + bi.x;
            float v1 = acc[1] + bi.y;
            float v2 = acc[2] + bi.z;
            float v3 = acc[3] + bi.w;
            if (!last) {
                half2v p0 = pk2(fmaxf(v0, 0.f), fmaxf(v1, 0.f));
                half2v p1 = pk2(fmaxf(v2, 0.f), fmaxf(v3, 0.f));
                half4 hv = __builtin_shufflevector(p0, p1, 0, 1, 2, 3);
                *reinterpret_cast<short4v*>(&hb_out[(size_t)node * DD + oc]) =
                    __builtin_bit_cast(short4v, hv);
            } else {
                float4 st; st.x = v0; st.y = v1; st.z = v2; st.w = v3;
                *reinterpret_cast<float4*>(&f_out[(size_t)node * DD + oc]) = st;
            }
        }
    }
}

extern "C" void kernel_launch(void* const* d_in, const int* in_sizes, int n_in,
                              void* d_out, int out_size, void* d_ws, size_t ws_size,
                              hipStream_t stream)
{
    const float* x  = (const float*)d_in[0];
    const int* ei   = (const int*)d_in[1];
    const int* src  = ei;
    const int* dst  = ei + EE;
    const float* W1 = (const float*)d_in[2];
    const float* b1 = (const float*)d_in[3];
    const float* g1 = (const float*)d_in[4];
    const float* bb1= (const float*)d_in[5];
    const float* m1 = (const float*)d_in[6];
    const float* v1 = (const float*)d_in[7];
    const float* W2 = (const float*)d_in[8];
    const float* b2 = (const float*)d_in[9];
    const float* g2 = (const float*)d_in[10];
    const float* bb2= (const float*)d_in[11];
    const float* m2 = (const float*)d_in[12];
    const float* v2 = (const float*)d_in[13];

    char* w = (char*)d_ws;
    short* hbufA = (short*)w;                                 // 25,600,000
    short* hbufB = (short*)(w + 25600000);                    // 25,600,000
    short* W1p   = (short*)(w + 51200000);                    //    327,680
    short* W2p   = (short*)(w + 51527680);                    //    327,680
    float* b1e   = (float*)(w + 51855360);                    //      5,120
    float* b2e   = (float*)(w + 51860480);                    //      2,560
    int*   cnt   = (int*)  (w + 51863040);                    //    400,000
    int*   cursor= (int*)  (w + 52263040);                    //    400,000 (contiguous after cnt)
    int*   rowst = (int*)  (w + 52663040);                    //    400,032
    int*   csr   = (int*)  (w + 53063072);                    //  2,560,000 (+64B pad)
    int*   bsum  = (int*)  (w + 55623136);                    //      1,664
    float* out   = (float*)d_out;

    // zero cnt + cursor (contiguous 800,000 B) — capture-safe async memset
    (void)hipMemsetAsync(cnt, 0, 800000, stream);
    setup<<<15640, 256, 0, stream>>>(W1, b1, g1, bb1, m1, v1,
                                     W2, b2, g2, bb2, m2, v2,
                                     x, dst, W1p, b1e, W2p, b2e, hbufA, cnt);
    scan_block<<<391, 256, 0, stream>>>(cnt, bsum);
    apply_offs2<<<391, 256, 0, stream>>>(cnt, bsum, rowst);
    fill_csr<<<2500, 256, 0, stream>>>(src, dst, rowst, cursor, csr);

    short* hin = hbufA;
    short* hout = hbufB;
    for (int l = 0; l < LL; ++l) {
        layer_fused<<<1563, 256, 0, stream>>>(hin, rowst, csr,
                                              W1p + l * 32768, b1e + l * HH,
                                              W2p + l * 32768, b2e + l * DD,
                                              hout, out, (l == LL - 1) ? 1 : 0);
        short* t = hin; hin = hout; hout = t;
    }
}

// Round 12
// 535.729 us; speedup vs baseline: 1.6114x; 1.6114x over previous
//
#include <hip/hip_runtime.h>

#define ND 100000
#define DD 128
#define HH 256
#define EE 640000
#define LL 5

// LDS view strides (in elements, fp16). 152/280 shorts = 76/140 words == 12 mod 32
#define GS 152   // gather view stride, 64 rows x 128 cols
#define ZS 280   // z view stride, 64 rows x 256 cols

typedef __attribute__((ext_vector_type(8))) short short8;
typedef __attribute__((ext_vector_type(4))) short short4v;
typedef __attribute__((ext_vector_type(4))) float f32x4;
typedef __attribute__((ext_vector_type(8))) _Float16 half8;
typedef __attribute__((ext_vector_type(4))) _Float16 half4;
typedef __attribute__((ext_vector_type(2))) _Float16 half2v;

static __device__ __forceinline__ short f2h(float f) {
    return __builtin_bit_cast(short, (_Float16)f);
}

// pack two fp32 -> packed fp16 pair (v_cvt_pkrtz_f16_f32, 1 instr)
static __device__ __forceinline__ half2v pk2(float a, float b) {
    return __builtin_bit_cast(half2v, __builtin_amdgcn_cvt_pkrtz(a, b));
}

// ---------------------------------------------------------------------------
// setup: blocks [0,640) fold BN into weights (fp16 pack, COALESCED reads,
//        scattered 2B writes — reads stall, writes don't);
//        blocks [640,13140) convert x fp32 -> fp16 into hbufA;
//        blocks [13140,15640) histogram dst degrees (cnt pre-zeroed).
// ---------------------------------------------------------------------------
__global__ __launch_bounds__(256) void setup(
    const float* __restrict__ W1, const float* __restrict__ b1,
    const float* __restrict__ g1, const float* __restrict__ bb1,
    const float* __restrict__ m1, const float* __restrict__ v1,
    const float* __restrict__ W2, const float* __restrict__ b2,
    const float* __restrict__ g2, const float* __restrict__ bb2,
    const float* __restrict__ m2, const float* __restrict__ v2,
    const float* __restrict__ x, const int* __restrict__ dst,
    short* __restrict__ W1p, float* __restrict__ b1e,
    short* __restrict__ W2p, float* __restrict__ b2e,
    short* __restrict__ hb, int* __restrict__ cnt)
{
    int bx = blockIdx.x;
    int tid = threadIdx.x;
    if (bx < 640) {
        int id = bx * 256 + tid;
        if (id < LL * HH * DD) {
            int l = id >> 15;
            int rem = id & 32767;
            {
                // W1 pack: coalesced read (consecutive tid -> consecutive n),
                // scattered write to W1p[l][n][k] ([256 zcols][128 k]).
                int k = rem >> 8, n = rem & 255;
                float s = g1[l * HH + n] * rsqrtf(v1[l * HH + n] + 1e-5f);
                W1p[l * 32768 + n * DD + k] = f2h(W1[l * 32768 + k * HH + n] * s);
            }
            {
                // W2 pack: coalesced read (consecutive tid -> consecutive n2),
                // scattered write to W2p[l][n2][k2] ([128 outcols][256 k]).
                int k2 = rem >> 7, n2 = rem & 127;
                float s = g2[l * DD + n2] * rsqrtf(v2[l * DD + n2] + 1e-5f);
                W2p[l * 32768 + n2 * HH + k2] = f2h(W2[l * 32768 + k2 * DD + n2] * s);
            }
        }
        if (id < LL * HH) {
            float s = g1[id] * rsqrtf(v1[id] + 1e-5f);
            b1e[id] = (b1[id] - m1[id]) * s + bb1[id];
        }
        if (id < LL * DD) {
            float s = g2[id] * rsqrtf(v2[id] + 1e-5f);
            b2e[id] = (b2[id] - m2[id]) * s + bb2[id];
        }
    } else if (bx < 13140) {
        int i = (bx - 640) * 256 + tid;          // ND*DD/4 = 3,200,000 float4s
        float4 v = reinterpret_cast<const float4*>(x)[i];
        half2v p0 = pk2(v.x, v.y);
        half2v p1 = pk2(v.z, v.w);
        half4 hv = __builtin_shufflevector(p0, p1, 0, 1, 2, 3);
        reinterpret_cast<short4v*>(hb)[i] = __builtin_bit_cast(short4v, hv);
    } else {
        int e = (bx - 13140) * 256 + tid;
        if (e < EE) atomicAdd(&cnt[dst[e]], 1);
    }
}

// per-block inclusive scan of cnt (in place) + block totals
__global__ __launch_bounds__(256) void scan_block(int* __restrict__ cnt, int* __restrict__ bsum)
{
    __shared__ int buf[256];
    int tid = threadIdx.x;
    int idx = blockIdx.x * 256 + tid;
    int v = (idx < ND) ? cnt[idx] : 0;
    buf[tid] = v;
    __syncthreads();
    int sum = v;
    for (int off = 1; off < 256; off <<= 1) {
        int t = (tid >= off) ? buf[tid - off] : 0;
        __syncthreads();
        sum += t;
        buf[tid] = sum;
        __syncthreads();
    }
    if (idx < ND) cnt[idx] = sum;
    if (tid == 255) bsum[blockIdx.x] = sum;
}

// each block computes its exclusive prefix over bsum, then rowst AND cursor
// (cursor[i] = rowst[i] = row start — fill_csr then needs no rowstart read).
__global__ __launch_bounds__(256) void apply_offs2(const int* __restrict__ cnt,
                                                   const int* __restrict__ bsum,
                                                   int* __restrict__ rowst,
                                                   int* __restrict__ cursor)
{
    __shared__ int sred[256];
    int tid = threadIdx.x;
    int partial = 0;
    for (int i = tid; i < blockIdx.x; i += 256) partial += bsum[i];
    sred[tid] = partial;
    __syncthreads();
    for (int off = 128; off > 0; off >>= 1) {
        if (tid < off) sred[tid] += sred[tid + off];
        __syncthreads();
    }
    int boff = sred[0];
    int idx = blockIdx.x * 256 + tid;
    if (idx < ND) {
        rowst[idx + 1] = cnt[idx] + boff;
        cursor[idx] = (tid == 0) ? boff : cnt[idx - 1] + boff;
    }
    if (idx == 0) rowst[0] = 0;
}

__global__ __launch_bounds__(256) void fill_csr(const int* __restrict__ src,
                                                const int* __restrict__ dst,
                                                int* __restrict__ cursor,
                                                int* __restrict__ csr)
{
    int e = blockIdx.x * 256 + threadIdx.x;
    if (e < EE) {
        int p = atomicAdd(&cursor[dst[e]], 1);
        csr[p] = src[e];
    }
}

// ---------------------------------------------------------------------------
// Fused GIN layer, 1024 threads (16 waves) per 64-row block (R6 — proven).
//   Stage A: gather. Per 16-lane row-group, csr indices are loaded 16-at-a-
//            time (ONE coalesced load per 16 edges) and distributed from
//            registers via __shfl; row loads issue in batches of 8.
//   GEMM1: wave owns 16 zcols x 64 nodes; aw1 preload issued pre-barrier.
//   GEMM2: wave owns 16 outcols x 32 nodes; W2 fragments software-pipelined.
// hb_in != hb_out (cross-block WAR hazard).
// LDS union: gather view stride 152, z view stride 280 (35,840 B).
// ---------------------------------------------------------------------------
__global__ __launch_bounds__(1024, 8) void layer_fused(
    const short* __restrict__ hb_in,
    const int* __restrict__ rowst,
    const int* __restrict__ csr,
    const short* __restrict__ W1l,    // [256][128] fp16
    const float* __restrict__ b1l,    // [256]
    const short* __restrict__ W2l,    // [128][256] fp16
    const float* __restrict__ b2l,    // [128]
    short* __restrict__ hb_out, float* __restrict__ f_out, int last)
{
    __shared__ __attribute__((aligned(16))) short sU[64 * ZS];   // 35,840 B

    const int tid = threadIdx.x;
    const int r0 = blockIdx.x * 64;
    const int wave = tid >> 6;
    const int lane = tid & 63;
    const int quad = lane >> 4;
    const int l16 = lane & 15;

    // ---- Stage A: neighbor gather, shfl-distributed indices, 8-deep loads ----
    {
        int row = tid >> 4;           // 0..63
        int ch = (tid & 15) * 8;      // 0,8,...,120
        int grow = r0 + row;
        const int gbase = lane & 48;  // 16-lane group base within wave
        half8 acc = {};
        if (grow < ND) {
            acc = __builtin_bit_cast(half8,
                *reinterpret_cast<const short8*>(&hb_in[(size_t)grow * DD + ch]));
            int s = rowst[grow], e = rowst[grow + 1];
            int deg = e - s;
            int i = s;
            while (deg > 0) {
                // one coalesced index load per 16 edges (csr padded 64B at end)
                int myidx = csr[i + (tid & 15)];
                int c = deg < 16 ? deg : 16;
                int done = 0;
                while (done < c) {
                    int cc = c - done; if (cc > 8) cc = 8;
                    half8 a[8];
                    #pragma unroll
                    for (int k = 0; k < 8; ++k) {
                        if (k < cc) {
                            int srcrow = __shfl(myidx, gbase + done + k, 64);
                            a[k] = __builtin_bit_cast(half8,
                                *reinterpret_cast<const short8*>(
                                    &hb_in[(size_t)srcrow * DD + ch]));
                        }
                    }
                    #pragma unroll
                    for (int k = 0; k < 8; ++k)
                        if (k < cc) acc = acc + a[k];
                    done += cc;
                }
                i += c; deg -= c;
            }
        }
        *reinterpret_cast<short8*>(&sU[row * GS + ch]) = __builtin_bit_cast(short8, acc);
    }

    // Preload GEMM1 weight fragments + bias (issued pre-barrier, used after)
    const int zrow = wave * 16 + l16;
    half8 aw1[4];
    for (int ks = 0; ks < 4; ++ks)
        aw1[ks] = __builtin_bit_cast(half8,
            *reinterpret_cast<const short8*>(&W1l[zrow * DD + ks * 32 + quad * 8]));
    float4 bias1 = *reinterpret_cast<const float4*>(&b1l[wave * 16 + quad * 4]);
    __syncthreads();

    // ---- GEMM1' zT = W1(A) x agg(B): wave owns zcols [wave*16,+16) x 64 nodes ----
    const f32x4 zero4 = {0.f, 0.f, 0.f, 0.f};
    f32x4 acc1[4];
    for (int nt = 0; nt < 4; ++nt) acc1[nt] = zero4;

    for (int ks = 0; ks < 4; ++ks) {
        int kofs = ks * 32 + quad * 8;
        for (int nt = 0; nt < 4; ++nt) {
            half8 bn = __builtin_bit_cast(half8,
                *reinterpret_cast<const short8*>(&sU[(nt * 16 + l16) * GS + kofs]));
            acc1[nt] = __builtin_amdgcn_mfma_f32_16x16x32_f16(aw1[ks], bn, acc1[nt], 0, 0, 0);
        }
    }
    __syncthreads();   // gather view dead; z view reuses LDS

    // ---- Stage C: bias + ReLU -> sU[node][zcol] (stride ZS), pk-f16 writes ----
    {
        int zc = wave * 16 + quad * 4;
        for (int nt = 0; nt < 4; ++nt) {
            int node = nt * 16 + l16;
            half2v p0 = pk2(fmaxf(acc1[nt][0] + bias1.x, 0.f),
                            fmaxf(acc1[nt][1] + bias1.y, 0.f));
            half2v p1 = pk2(fmaxf(acc1[nt][2] + bias1.z, 0.f),
                            fmaxf(acc1[nt][3] + bias1.w, 0.f));
            half4 hv = __builtin_shufflevector(p0, p1, 0, 1, 2, 3);
            *reinterpret_cast<short4v*>(&sU[node * ZS + zc]) = __builtin_bit_cast(short4v, hv);
        }
    }

    // Preload GEMM2 first weight fragment + bias while barrier settles
    const int ct16 = wave >> 1;
    const int nh = wave & 1;
    const int orow = ct16 * 16 + l16;
    half8 w_cur = __builtin_bit_cast(half8,
        *reinterpret_cast<const short8*>(&W2l[orow * HH + quad * 8]));
    float4 bias2 = *reinterpret_cast<const float4*>(&b2l[ct16 * 16 + quad * 4]);
    __syncthreads();

    // ---- GEMM2' hT = W2(A) x z(B): wave owns outcols [ct16*16,+16) x 32 nodes,
    //      W2 fragments software-pipelined ----
    f32x4 acc2[2];
    for (int nt = 0; nt < 2; ++nt) acc2[nt] = zero4;

    for (int ks = 0; ks < 8; ++ks) {
        half8 w_next;
        if (ks < 7)
            w_next = __builtin_bit_cast(half8,
                *reinterpret_cast<const short8*>(&W2l[orow * HH + (ks + 1) * 32 + quad * 8]));
        int kofs = ks * 32 + quad * 8;
        for (int nt = 0; nt < 2; ++nt) {
            int node = nh * 32 + nt * 16 + l16;
            half8 bn = __builtin_bit_cast(half8,
                *reinterpret_cast<const short8*>(&sU[node * ZS + kofs]));
            acc2[nt] = __builtin_amdgcn_mfma_f32_16x16x32_f16(w_cur, bn, acc2[nt], 0, 0, 0);
        }
        w_cur = w_next;
    }

    // ---- Stage E: bias (+ReLU) -> vectorized global stores ----
    {
        int oc = ct16 * 16 + quad * 4;
        for (int nt = 0; nt < 2; ++nt) {
            int node = r0 + nh * 32 + nt * 16 + l16;
            if (node < ND) {
                float v0 = acc2[nt][0] + bias2.x;
                float v1 = acc2[nt][1] + bias2.y;
                float v2 = acc2[nt][2] + bias2.z;
                float v3 = acc2[nt][3] + bias2.w;
                if (!last) {
                    half2v p0 = pk2(fmaxf(v0, 0.f), fmaxf(v1, 0.f));
                    half2v p1 = pk2(fmaxf(v2, 0.f), fmaxf(v3, 0.f));
                    half4 hv = __builtin_shufflevector(p0, p1, 0, 1, 2, 3);
                    *reinterpret_cast<short4v*>(&hb_out[(size_t)node * DD + oc]) =
                        __builtin_bit_cast(short4v, hv);
                } else {
                    float4 st; st.x = v0; st.y = v1; st.z = v2; st.w = v3;
                    *reinterpret_cast<float4*>(&f_out[(size_t)node * DD + oc]) = st;
                }
            }
        }
    }
}

extern "C" void kernel_launch(void* const* d_in, const int* in_sizes, int n_in,
                              void* d_out, int out_size, void* d_ws, size_t ws_size,
                              hipStream_t stream)
{
    const float* x  = (const float*)d_in[0];
    const int* ei   = (const int*)d_in[1];
    const int* src  = ei;
    const int* dst  = ei + EE;
    const float* W1 = (const float*)d_in[2];
    const float* b1 = (const float*)d_in[3];
    const float* g1 = (const float*)d_in[4];
    const float* bb1= (const float*)d_in[5];
    const float* m1 = (const float*)d_in[6];
    const float* v1 = (const float*)d_in[7];
    const float* W2 = (const float*)d_in[8];
    const float* b2 = (const float*)d_in[9];
    const float* g2 = (const float*)d_in[10];
    const float* bb2= (const float*)d_in[11];
    const float* m2 = (const float*)d_in[12];
    const float* v2 = (const float*)d_in[13];

    char* w = (char*)d_ws;
    short* hbufA = (short*)w;                                 // 25,600,000
    short* hbufB = (short*)(w + 25600000);                    // 25,600,000
    short* W1p   = (short*)(w + 51200000);                    //    327,680
    short* W2p   = (short*)(w + 51527680);                    //    327,680
    float* b1e   = (float*)(w + 51855360);                    //      5,120
    float* b2e   = (float*)(w + 51860480);                    //      2,560
    int*   cnt   = (int*)  (w + 51863040);                    //    400,000
    int*   cursor= (int*)  (w + 52263040);                    //    400,000
    int*   rowst = (int*)  (w + 52663040);                    //    400,032
    int*   csr   = (int*)  (w + 53063072);                    //  2,560,000 (+64B pad)
    int*   bsum  = (int*)  (w + 55623136);                    //      1,664
    float* out   = (float*)d_out;

    // zero cnt only (cursor is fully written by apply_offs2)
    (void)hipMemsetAsync(cnt, 0, 400000, stream);
    setup<<<15640, 256, 0, stream>>>(W1, b1, g1, bb1, m1, v1,
                                     W2, b2, g2, bb2, m2, v2,
                                     x, dst, W1p, b1e, W2p, b2e, hbufA, cnt);
    scan_block<<<391, 256, 0, stream>>>(cnt, bsum);
    apply_offs2<<<391, 256, 0, stream>>>(cnt, bsum, rowst, cursor);
    fill_csr<<<2500, 256, 0, stream>>>(src, dst, cursor, csr);

    short* hin = hbufA;
    short* hout = hbufB;
    for (int l = 0; l < LL; ++l) {
        layer_fused<<<1563, 1024, 0, stream>>>(hin, rowst, csr,
                                               W1p + l * 32768, b1e + l * HH,
                                               W2p + l * 32768, b2e + l * DD,
                                               hout, out, (l == LL - 1) ? 1 : 0);
        short* t = hin; hin = hout; hout = t;
    }
}